// Round 1
// baseline (87.075 us; speedup 1.0000x reference)
//
#include <hip/hip_runtime.h>

// FidelityKernel: K[i,j] = |perm( (U2[j][:, :6])^H @ (U1[i][:, :6]) )|^2 / 1024
// with U(x) = A @ diag(e^{ix}) @ B, Glynn permanent via Gray-code enumeration.

#define NS 384      // samples per side
#define MM 12       // modes
#define NP 6        // photons (submatrix size)
#define TS 16       // pair-tile edge (16x16 pairs per block = 256 threads)
#define SV_STRIDE 148  // 144 payload floats + 4 pad (LDS bank-conflict mitigation)

struct c32 { float x, y; };

__device__ __forceinline__ c32 cmul(c32 a, c32 b) {
    c32 r;
    r.x = a.x * b.x - a.y * b.y;
    r.y = a.x * b.y + a.y * b.x;
    return r;
}

// Build V1[s][k][c] = U1(x1_s)[k,c] and V2c[s][k][c] = conj(U2(x2_s)[k,c]) for c<6.
// U[a][c] = sum_b A[a,b] * e^{i x_b} * B[b,c]. One thread per (half, sample, column).
__global__ void build_V_kernel(const float* __restrict__ x1,
                               const float* __restrict__ x2,
                               const float* __restrict__ Ar, const float* __restrict__ Ai,
                               const float* __restrict__ Br, const float* __restrict__ Bi,
                               float* __restrict__ V1, float* __restrict__ V2c) {
    int idx = blockIdx.x * blockDim.x + threadIdx.x;
    if (idx >= 2 * NS * NP) return;
    int half = idx / (NS * NP);
    int rem  = idx - half * (NS * NP);
    int s = rem / NP, c = rem - s * NP;
    const float* x = half ? x2 : x1;

    // t[b] = e^{i x[s,b]} * B[b,c]
    float tr[MM], ti[MM];
#pragma unroll
    for (int b = 0; b < MM; ++b) {
        float sv, cv;
        sincosf(x[s * MM + b], &sv, &cv);
        float br = Br[b * MM + c], bi = Bi[b * MM + c];
        tr[b] = cv * br - sv * bi;
        ti[b] = cv * bi + sv * br;
    }

    float* V = half ? V2c : V1;
    float sgn = half ? -1.f : 1.f;   // conjugate U2 at store time
#pragma unroll
    for (int a = 0; a < MM; ++a) {
        float ure = 0.f, uim = 0.f;
#pragma unroll
        for (int b = 0; b < MM; ++b) {
            float ar = Ar[a * MM + b], ai = Ai[a * MM + b];
            ure = fmaf(ar, tr[b], fmaf(-ai, ti[b], ure));
            uim = fmaf(ar, ti[b], fmaf( ai, tr[b], uim));
        }
        int off = ((s * MM + a) * NP + c) * 2;
        V[off]     = ure;
        V[off + 1] = sgn * uim;
    }
}

// One thread per (i,j) pair. Block = 16x16 pairs; stage 16 rows of each V in LDS.
__global__ __launch_bounds__(256) void perm_kernel(const float* __restrict__ V1g,
                                                   const float* __restrict__ V2g,
                                                   float* __restrict__ out) {
    __shared__ __align__(16) float sV1[TS * SV_STRIDE];
    __shared__ __align__(16) float sV2[TS * SV_STRIDE];
    const int i0 = blockIdx.y * TS;
    const int j0 = blockIdx.x * TS;
    const int tid = threadIdx.x;

    // Stage 16 samples x 144 floats (36 float4) from each array.
    for (int idx = tid; idx < 2 * TS * 36; idx += 256) {
        int which = idx >= TS * 36;
        int rem = which ? idx - TS * 36 : idx;
        int s = rem / 36, q = rem - s * 36;
        const float* src = which ? (V2g + (j0 + s) * 144) : (V1g + (i0 + s) * 144);
        float4 v = *(const float4*)(src + q * 4);
        float* dst = (which ? sV2 : sV1) + s * SV_STRIDE + q * 4;
        *(float4*)dst = v;
    }
    __syncthreads();

    const int tx = tid & 15, ty = tid >> 4;
    const float* v1 = sV1 + ty * SV_STRIDE;  // broadcast across tx lanes
    const float* v2 = sV2 + tx * SV_STRIDE;  // stride 148 floats -> <=2-way banks

    // W[a][b] = sum_k conj(U2[j,k,a]) * U1[i,k,b]  (conj baked into V2)
    c32 W[NP][NP];
#pragma unroll
    for (int a = 0; a < NP; ++a)
#pragma unroll
        for (int b = 0; b < NP; ++b) { W[a][b].x = 0.f; W[a][b].y = 0.f; }

#pragma unroll
    for (int k = 0; k < MM; ++k) {
        float4 p1[3], p2[3];
#pragma unroll
        for (int q = 0; q < 3; ++q) {
            p1[q] = *(const float4*)(v1 + k * 12 + q * 4);
            p2[q] = *(const float4*)(v2 + k * 12 + q * 4);
        }
        const float* f1 = (const float*)p1;
        const float* f2 = (const float*)p2;
#pragma unroll
        for (int a = 0; a < NP; ++a) {
            float a2x = f2[2 * a], a2y = f2[2 * a + 1];
#pragma unroll
            for (int b = 0; b < NP; ++b) {
                float a1x = f1[2 * b], a1y = f1[2 * b + 1];
                W[a][b].x = fmaf(a2x, a1x, fmaf(-a2y, a1y, W[a][b].x));
                W[a][b].y = fmaf(a2x, a1y, fmaf( a2y, a1x, W[a][b].y));
            }
        }
    }

    // Glynn permanent, Gray-code order. rs[b] = sum_a delta_a * W[a][b].
    c32 rs[NP];
#pragma unroll
    for (int b = 0; b < NP; ++b) {
        rs[b] = W[0][b];
#pragma unroll
        for (int a = 1; a < NP; ++a) { rs[b].x += W[a][b].x; rs[b].y += W[a][b].y; }
    }

    c32 acc;
    {
        c32 p = rs[0];
#pragma unroll
        for (int b = 1; b < NP; ++b) p = cmul(p, rs[b]);
        acc = p;  // t=0: all deltas +1, parity +1
    }

    unsigned state = 0;  // bits for delta_1..delta_5 (0 => +1)
#pragma unroll
    for (int t = 1; t < 32; ++t) {
        const int bitpos = __builtin_ctz(t);  // compile-time after unroll
        const int r = bitpos + 1;             // row being flipped (row 0 fixed +1)
        float cf = ((state >> bitpos) & 1) ? 2.f : -2.f;
        state ^= (1u << bitpos);
#pragma unroll
        for (int b = 0; b < NP; ++b) {
            rs[b].x = fmaf(cf, W[r][b].x, rs[b].x);
            rs[b].y = fmaf(cf, W[r][b].y, rs[b].y);
        }
        c32 p = rs[0];
#pragma unroll
        for (int b = 1; b < NP; ++b) p = cmul(p, rs[b]);
        float par = (t & 1) ? -1.f : 1.f;  // parity = (-1)^popcount(gray(t))
        acc.x = fmaf(par, p.x, acc.x);
        acc.y = fmaf(par, p.y, acc.y);
    }

    // perm = acc / 32; K = |perm|^2
    float K = (acc.x * acc.x + acc.y * acc.y) * (1.f / 1024.f);
    out[(i0 + ty) * NS + (j0 + tx)] = K;
}

extern "C" void kernel_launch(void* const* d_in, const int* in_sizes, int n_in,
                              void* d_out, int out_size, void* d_ws, size_t ws_size,
                              hipStream_t stream) {
    const float* x1 = (const float*)d_in[0];
    const float* x2 = (const float*)d_in[1];
    const float* Ar = (const float*)d_in[2];
    const float* Ai = (const float*)d_in[3];
    const float* Br = (const float*)d_in[4];
    const float* Bi = (const float*)d_in[5];
    float* out = (float*)d_out;

    float* V1  = (float*)d_ws;                  // 384*12*6*2 floats = 221184 B
    float* V2c = V1 + NS * MM * NP * 2;         // same size again

    int total = 2 * NS * NP;  // 4608 threads
    build_V_kernel<<<(total + 255) / 256, 256, 0, stream>>>(x1, x2, Ar, Ai, Br, Bi, V1, V2c);

    dim3 grid(NS / TS, NS / TS);  // 24 x 24
    perm_kernel<<<grid, 256, 0, stream>>>(V1, V2c, out);
}

// Round 2
// 80.730 us; speedup vs baseline: 1.0786x; 1.0786x over previous
//
#include <hip/hip_runtime.h>

// FidelityKernel: K[i,j] = |perm( (U2[j][:, :6])^H @ (U1[i][:, :6]) )|^2 / 1024
// with U(x) = A @ diag(e^{ix}) @ B, Glynn permanent via 4 independent
// Gray-code chains (split on delta_4, delta_5) for 4x ILP in the serial part.

#define NS 384      // samples per side
#define MM 12       // modes
#define NP 6        // photons (submatrix size)
#define TS 16       // pair-tile edge (16x16 pairs per block = 256 threads)
#define SV_STRIDE 148  // 144 payload floats + 4 pad (bank-conflict mitigation)

struct c32 { float x, y; };

__device__ __forceinline__ c32 cmul(c32 a, c32 b) {
    c32 r;
    r.x = fmaf(a.x, b.x, -a.y * b.y);
    r.y = fmaf(a.x, b.y,  a.y * b.x);
    return r;
}

// V1[s][k][c] = U1(x1_s)[k,c], V2c[s][k][c] = conj(U2(x2_s)[k,c]), c<6.
// One thread per (half, sample, column, row-half). 9216 threads.
__global__ void build_V_kernel(const float* __restrict__ x1,
                               const float* __restrict__ x2,
                               const float* __restrict__ Ar, const float* __restrict__ Ai,
                               const float* __restrict__ Br, const float* __restrict__ Bi,
                               float* __restrict__ V1, float* __restrict__ V2c) {
    int idx = blockIdx.x * blockDim.x + threadIdx.x;
    if (idx >= 2 * NS * NP * 2) return;
    int ah = idx & 1;
    int rest = idx >> 1;
    int c = rest % NP; rest /= NP;
    int s = rest % NS;
    int half = rest / NS;
    const float* x = half ? x2 : x1;

    // t[b] = e^{i x[s,b]} * B[b,c]
    float tr[MM], ti[MM];
#pragma unroll
    for (int b = 0; b < MM; ++b) {
        float sv, cv;
        __sincosf(x[s * MM + b], &sv, &cv);   // hw v_sin/v_cos; |x|~N(0,1) -> safe
        float br = Br[b * MM + c], bi = Bi[b * MM + c];
        tr[b] = fmaf(cv, br, -sv * bi);
        ti[b] = fmaf(cv, bi,  sv * br);
    }

    float* V = half ? V2c : V1;
    float sgn = half ? -1.f : 1.f;   // conjugate U2 at store time
#pragma unroll
    for (int a0 = 0; a0 < NP; ++a0) {
        int a = ah * NP + a0;
        float ure = 0.f, uim = 0.f;
#pragma unroll
        for (int b = 0; b < MM; ++b) {
            float ar = Ar[a * MM + b], ai = Ai[a * MM + b];
            ure = fmaf(ar, tr[b], fmaf(-ai, ti[b], ure));
            uim = fmaf(ar, ti[b], fmaf( ai, tr[b], uim));
        }
        int off = ((s * MM + a) * NP + c) * 2;
        V[off]     = ure;
        V[off + 1] = sgn * uim;
    }
}

__device__ __forceinline__ c32 tree_prod(const c32 rs[NP]) {
    c32 p01 = cmul(rs[0], rs[1]);
    c32 p23 = cmul(rs[2], rs[3]);
    c32 p45 = cmul(rs[4], rs[5]);
    return cmul(cmul(p01, p23), p45);
}

// One thread per (i,j) pair. Block = 16x16 pairs; 16 rows of each V in LDS.
__global__ __launch_bounds__(256) void perm_kernel(const float* __restrict__ V1g,
                                                   const float* __restrict__ V2g,
                                                   float* __restrict__ out) {
    __shared__ __align__(16) float sV1[TS * SV_STRIDE];
    __shared__ __align__(16) float sV2[TS * SV_STRIDE];
    const int i0 = blockIdx.y * TS;
    const int j0 = blockIdx.x * TS;
    const int tid = threadIdx.x;

    // Stage 16 samples x 144 floats (36 float4) from each array.
    for (int idx = tid; idx < 2 * TS * 36; idx += 256) {
        int which = idx >= TS * 36;
        int rem = which ? idx - TS * 36 : idx;
        int s = rem / 36, q = rem - s * 36;
        const float* src = which ? (V2g + (j0 + s) * 144) : (V1g + (i0 + s) * 144);
        float4 v = *(const float4*)(src + q * 4);
        float* dst = (which ? sV2 : sV1) + s * SV_STRIDE + q * 4;
        *(float4*)dst = v;
    }
    __syncthreads();

    const int tx = tid & 15, ty = tid >> 4;
    const float* v1 = sV1 + ty * SV_STRIDE;  // broadcast across tx lanes
    const float* v2 = sV2 + tx * SV_STRIDE;

    // W[a][b] = sum_k conj(U2[j,k,a]) * U1[i,k,b]  (conj baked into V2)
    c32 W[NP][NP];
#pragma unroll
    for (int a = 0; a < NP; ++a)
#pragma unroll
        for (int b = 0; b < NP; ++b) { W[a][b].x = 0.f; W[a][b].y = 0.f; }

#pragma unroll
    for (int k = 0; k < MM; ++k) {
        float4 p1[3], p2[3];
#pragma unroll
        for (int q = 0; q < 3; ++q) {
            p1[q] = *(const float4*)(v1 + k * 12 + q * 4);
            p2[q] = *(const float4*)(v2 + k * 12 + q * 4);
        }
        const float* f1 = (const float*)p1;
        const float* f2 = (const float*)p2;
#pragma unroll
        for (int a = 0; a < NP; ++a) {
            float a2x = f2[2 * a], a2y = f2[2 * a + 1];
#pragma unroll
            for (int b = 0; b < NP; ++b) {
                float a1x = f1[2 * b], a1y = f1[2 * b + 1];
                W[a][b].x = fmaf(a2x, a1x, fmaf(-a2y, a1y, W[a][b].x));
                W[a][b].y = fmaf(a2x, a1y, fmaf( a2y, a1x, W[a][b].y));
            }
        }
    }

    // Glynn permanent: delta_0 = +1; bits s_0..s_4 <-> delta_1..delta_5.
    // Split on (s_3, s_4) -> 4 independent chains, each Gray-coding s_0..s_2.
    c32 base[NP];
#pragma unroll
    for (int b = 0; b < NP; ++b) {
        base[b] = W[0][b];
#pragma unroll
        for (int a = 1; a < NP; ++a) { base[b].x += W[a][b].x; base[b].y += W[a][b].y; }
    }

    c32 rs[4][NP];
#pragma unroll
    for (int b = 0; b < NP; ++b) {
        rs[0][b] = base[b];                                             // s3=0,s4=0
        rs[1][b].x = fmaf(-2.f, W[4][b].x, base[b].x);                  // s3=1 (delta_4=-1)
        rs[1][b].y = fmaf(-2.f, W[4][b].y, base[b].y);
        rs[2][b].x = fmaf(-2.f, W[5][b].x, base[b].x);                  // s4=1 (delta_5=-1)
        rs[2][b].y = fmaf(-2.f, W[5][b].y, base[b].y);
        rs[3][b].x = fmaf(-2.f, W[5][b].x, rs[1][b].x);                 // both
        rs[3][b].y = fmaf(-2.f, W[5][b].y, rs[1][b].y);
    }
    // chain parity at u=0: (-1)^{s3+s4} = {+1, -1, -1, +1}
    float accx[4], accy[4];
#pragma unroll
    for (int ch = 0; ch < 4; ++ch) {
        c32 p = tree_prod(rs[ch]);
        accx[ch] = p.x; accy[ch] = p.y;
    }

    unsigned st = 0;  // Gray state of s_0..s_2 (same sequence for all chains)
#pragma unroll
    for (int u = 1; u < 8; ++u) {
        const int bitpos = __builtin_ctz(u);   // compile-time after unroll
        const int r = bitpos + 1;              // row flipped (rows 1..3)
        float cf = ((st >> bitpos) & 1) ? 2.f : -2.f;
        st ^= (1u << bitpos);
        float sgn_u = (u & 1) ? -1.f : 1.f;    // (-1)^popcount(gray(u))
#pragma unroll
        for (int ch = 0; ch < 4; ++ch) {
#pragma unroll
            for (int b = 0; b < NP; ++b) {
                rs[ch][b].x = fmaf(cf, W[r][b].x, rs[ch][b].x);
                rs[ch][b].y = fmaf(cf, W[r][b].y, rs[ch][b].y);
            }
            c32 p = tree_prod(rs[ch]);
            accx[ch] = fmaf(sgn_u, p.x, accx[ch]);
            accy[ch] = fmaf(sgn_u, p.y, accy[ch]);
        }
    }

    float ax = accx[0] - accx[1] - accx[2] + accx[3];
    float ay = accy[0] - accy[1] - accy[2] + accy[3];
    // perm = acc / 32; K = |perm|^2
    float K = fmaf(ax, ax, ay * ay) * (1.f / 1024.f);
    out[(i0 + ty) * NS + (j0 + tx)] = K;
}

extern "C" void kernel_launch(void* const* d_in, const int* in_sizes, int n_in,
                              void* d_out, int out_size, void* d_ws, size_t ws_size,
                              hipStream_t stream) {
    const float* x1 = (const float*)d_in[0];
    const float* x2 = (const float*)d_in[1];
    const float* Ar = (const float*)d_in[2];
    const float* Ai = (const float*)d_in[3];
    const float* Br = (const float*)d_in[4];
    const float* Bi = (const float*)d_in[5];
    float* out = (float*)d_out;

    float* V1  = (float*)d_ws;                  // 384*12*6*2 floats
    float* V2c = V1 + NS * MM * NP * 2;

    int total = 2 * NS * NP * 2;  // 9216 threads
    build_V_kernel<<<(total + 255) / 256, 256, 0, stream>>>(x1, x2, Ar, Ai, Br, Bi, V1, V2c);

    dim3 grid(NS / TS, NS / TS);  // 24 x 24
    perm_kernel<<<grid, 256, 0, stream>>>(V1, V2c, out);
}

// Round 3
// 78.493 us; speedup vs baseline: 1.1093x; 1.0285x over previous
//
#include <hip/hip_runtime.h>

// FidelityKernel: K[i,j] = |perm( (U2[j][:, :6])^H @ (U1[i][:, :6]) )|^2 / 1024
// Complex math on float2 ext-vectors -> v_pk_fma_f32 (2x FP32 packed VALU).
// Glynn permanent via 4 independent Gray-code chains (split on delta_4/delta_5).

typedef float v2f __attribute__((ext_vector_type(2)));

#define NS 384      // samples per side
#define MM 12       // modes
#define NP 6        // photons (submatrix size)
#define TS 16       // pair-tile edge (16x16 pairs per block = 256 threads)
#define SV_STRIDE 148  // 144 payload floats + 4 pad

// complex multiply: (a.x + i a.y)(b.x + i b.y)
__device__ __forceinline__ v2f cmul(v2f a, v2f b) {
    v2f r = (v2f){a.x, a.x} * b;
    return __builtin_elementwise_fma((v2f){a.y, a.y}, (v2f){-b.y, b.x}, r);
}
// acc += a*b (complex)
__device__ __forceinline__ v2f cmac(v2f acc, v2f a, v2f b) {
    acc = __builtin_elementwise_fma((v2f){a.x, a.x}, b, acc);
    return __builtin_elementwise_fma((v2f){a.y, a.y}, (v2f){-b.y, b.x}, acc);
}

// V1[s][k][c] = U1(x1_s)[k,c], V2c[s][k][c] = conj(U2(x2_s)[k,c]), c<6.
// Scatter: one thread per (half, s, a, c) -> 55296 threads (864 waves).
__global__ void build_V_kernel(const float* __restrict__ x1,
                               const float* __restrict__ x2,
                               const float* __restrict__ Ar, const float* __restrict__ Ai,
                               const float* __restrict__ Br, const float* __restrict__ Bi,
                               float* __restrict__ V1, float* __restrict__ V2c) {
    int idx = blockIdx.x * blockDim.x + threadIdx.x;
    if (idx >= 2 * NS * MM * NP) return;
    int c = idx % NP;  int rest = idx / NP;
    int a = rest % MM; rest /= MM;
    int s = rest % NS; int half = rest / NS;
    const float* x = half ? x2 : x1;

    v2f u = {0.f, 0.f};
#pragma unroll
    for (int b = 0; b < MM; ++b) {
        float sv, cv;
        __sincosf(x[s * MM + b], &sv, &cv);   // hw v_sin/v_cos; x ~ N(0,1)
        v2f ph = {cv, sv};
        v2f Bv = {Br[b * MM + c], Bi[b * MM + c]};
        v2f t  = cmul(ph, Bv);
        v2f Av = {Ar[a * MM + b], Ai[a * MM + b]};
        u = cmac(u, Av, t);
    }
    float* V = half ? V2c : V1;
    int off = ((s * MM + a) * NP + c) * 2;
    V[off]     = u.x;
    V[off + 1] = half ? -u.y : u.y;   // conjugate U2 at store time
}

__device__ __forceinline__ v2f tree_prod(const v2f rs[NP]) {
    v2f p01 = cmul(rs[0], rs[1]);
    v2f p23 = cmul(rs[2], rs[3]);
    v2f p45 = cmul(rs[4], rs[5]);
    return cmul(cmul(p01, p23), p45);
}

// One thread per (i,j) pair. Block = 16x16 pairs; 16 rows of each V in LDS.
__global__ __launch_bounds__(256) void perm_kernel(const float* __restrict__ V1g,
                                                   const float* __restrict__ V2g,
                                                   float* __restrict__ out) {
    __shared__ __align__(16) float sV1[TS * SV_STRIDE];
    __shared__ __align__(16) float sV2[TS * SV_STRIDE];
    const int i0 = blockIdx.y * TS;
    const int j0 = blockIdx.x * TS;
    const int tid = threadIdx.x;

    // Stage 16 samples x 144 floats (36 float4) from each array.
    for (int idx = tid; idx < 2 * TS * 36; idx += 256) {
        int which = idx >= TS * 36;
        int rem = which ? idx - TS * 36 : idx;
        int s = rem / 36, q = rem - s * 36;
        const float* src = which ? (V2g + (j0 + s) * 144) : (V1g + (i0 + s) * 144);
        float4 v = *(const float4*)(src + q * 4);
        float* dst = (which ? sV2 : sV1) + s * SV_STRIDE + q * 4;
        *(float4*)dst = v;
    }
    __syncthreads();

    const int tx = tid & 15, ty = tid >> 4;
    const float* v1 = sV1 + ty * SV_STRIDE;  // broadcast across tx lanes
    const float* v2 = sV2 + tx * SV_STRIDE;  // 2-way max aliasing (free)

    // W[a][b] = sum_k conj(U2[j,k,a]) * U1[i,k,b]  (conj baked into V2)
    v2f W[NP][NP];
#pragma unroll
    for (int a = 0; a < NP; ++a)
#pragma unroll
        for (int b = 0; b < NP; ++b) W[a][b] = (v2f){0.f, 0.f};

#pragma unroll
    for (int k = 0; k < MM; ++k) {
        const v2f* c1 = (const v2f*)(v1 + k * 12);
        const v2f* c2 = (const v2f*)(v2 + k * 12);
        v2f a1[NP], a2[NP];
#pragma unroll
        for (int b = 0; b < NP; ++b) { a1[b] = c1[b]; a2[b] = c2[b]; }
#pragma unroll
        for (int a = 0; a < NP; ++a)
#pragma unroll
            for (int b = 0; b < NP; ++b)
                W[a][b] = cmac(W[a][b], a2[a], a1[b]);
    }

    // Glynn: delta_0 = +1; bits s_0..s_4 <-> delta_1..delta_5.
    // Split on (s_3, s_4) -> 4 independent chains Gray-coding s_0..s_2.
    v2f base[NP];
#pragma unroll
    for (int b = 0; b < NP; ++b) {
        base[b] = W[0][b];
#pragma unroll
        for (int a = 1; a < NP; ++a) base[b] += W[a][b];
    }

    v2f rs[4][NP];
#pragma unroll
    for (int b = 0; b < NP; ++b) {
        v2f m2 = {-2.f, -2.f};
        rs[0][b] = base[b];
        rs[1][b] = __builtin_elementwise_fma(m2, W[4][b], base[b]);   // delta_4 = -1
        rs[2][b] = __builtin_elementwise_fma(m2, W[5][b], base[b]);   // delta_5 = -1
        rs[3][b] = __builtin_elementwise_fma(m2, W[5][b], rs[1][b]);  // both
    }
    // chain parity at u=0: (-1)^{s3+s4} = {+1, -1, -1, +1}
    v2f acc[4];
#pragma unroll
    for (int ch = 0; ch < 4; ++ch) acc[ch] = tree_prod(rs[ch]);

    unsigned st = 0;  // Gray state of s_0..s_2 (shared by all chains)
#pragma unroll
    for (int u = 1; u < 8; ++u) {
        const int bitpos = __builtin_ctz(u);   // compile-time after unroll
        const int r = bitpos + 1;              // row flipped (rows 1..3)
        float cf = ((st >> bitpos) & 1) ? 2.f : -2.f;
        st ^= (1u << bitpos);
        float sgn_u = (u & 1) ? -1.f : 1.f;    // (-1)^popcount(gray(u))
        v2f cfv = {cf, cf};
        v2f sgv = {sgn_u, sgn_u};
#pragma unroll
        for (int ch = 0; ch < 4; ++ch) {
#pragma unroll
            for (int b = 0; b < NP; ++b)
                rs[ch][b] = __builtin_elementwise_fma(cfv, W[r][b], rs[ch][b]);
            v2f p = tree_prod(rs[ch]);
            acc[ch] = __builtin_elementwise_fma(sgv, p, acc[ch]);
        }
    }

    v2f aa = acc[0] - acc[1] - acc[2] + acc[3];
    // perm = aa / 32; K = |perm|^2
    float K = fmaf(aa.x, aa.x, aa.y * aa.y) * (1.f / 1024.f);
    out[(i0 + ty) * NS + (j0 + tx)] = K;
}

extern "C" void kernel_launch(void* const* d_in, const int* in_sizes, int n_in,
                              void* d_out, int out_size, void* d_ws, size_t ws_size,
                              hipStream_t stream) {
    const float* x1 = (const float*)d_in[0];
    const float* x2 = (const float*)d_in[1];
    const float* Ar = (const float*)d_in[2];
    const float* Ai = (const float*)d_in[3];
    const float* Br = (const float*)d_in[4];
    const float* Bi = (const float*)d_in[5];
    float* out = (float*)d_out;

    float* V1  = (float*)d_ws;                  // 384*12*6*2 floats
    float* V2c = V1 + NS * MM * NP * 2;

    int total = 2 * NS * MM * NP;  // 55296 threads
    build_V_kernel<<<(total + 255) / 256, 256, 0, stream>>>(x1, x2, Ar, Ai, Br, Bi, V1, V2c);

    dim3 grid(NS / TS, NS / TS);  // 24 x 24
    perm_kernel<<<grid, 256, 0, stream>>>(V1, V2c, out);
}